// Round 11
// baseline (274.663 us; speedup 1.0000x reference)
//
#include <hip/hip_runtime.h>
#include <hip/hip_bf16.h>

typedef float f32x4 __attribute__((ext_vector_type(4)));
typedef float f32x2 __attribute__((ext_vector_type(2)));
typedef _Float16 f16x8 __attribute__((ext_vector_type(8)));
typedef _Float16 f16x2 __attribute__((ext_vector_type(2)));
typedef __fp16 h16x2 __attribute__((ext_vector_type(2)));   // builtin's return type

#define HH 512
#define WW 512
#define NPLANES 48              // B*C = 16*3
#define KSIZE 23
#define NBLK (16 * 16 * NPLANES)
#define C1V 1.0e-4f             // 0.01^2
#define C2V 9.0e-4f             // 0.03^2

// Round-20: SA/SB staging DELETED. Each thread loads its own h-pass A/B
// fragments straight from global (8 predicated float4, issued at kernel top,
// consumed via register vmcnt — NO barrier on the staging->compute path;
// this is what round-1 and round-9 got wrong: their global reads sat behind
// barriers). Junk rows 55..63 load real/zero data — finite, killed by the
// structurally-zero v-pass G taps (k>=row+1 => taps for k in [55,64) are 0).
// LDS now: HB [0,8192) 4ch x 32col x 64row (pitch 64 + SWZ), G [8192,10240).
// 20480 B. Barriers: G-copy, HB, swsum = 3 (was 4).
#define HB_O   0
#define HB_CH  2048
#define G_O    8192
#define LDS_TOT 10240

// XOR bank swizzle within a pitch-64 region; preserves 8-ushort (16B) blocks.
#define SWZ(rho, k) ((k) ^ (((rho) & 7) << 3))

// pack two fp32 -> fp16 pair (lo = a, hi = b), RTZ (v_cvt_pkrtz_f16_f32, 1 inst)
__device__ __forceinline__ unsigned cvtpk(float a, float b) {
    union { h16x2 h; unsigned u; } cv;
    cv.h = __builtin_amdgcn_cvt_pkrtz(a, b);
    return cv.u;
}

// Packed fp16 products: pab = a*b, pss = a*a + b*b (v_pk_mul + v_pk_fma).
__device__ __forceinline__ void prod2(unsigned a, unsigned b,
                                      unsigned& pab, unsigned& pss) {
    union U { f16x2 h; unsigned u; } ua, ub, r1, r2;
    ua.u = a; ub.u = b;
    r1.h = ua.h * ub.h;
    r2.h = ua.h * ua.h + ub.h * ub.h;
    pab = r1.u; pss = r2.u;
}

__device__ __forceinline__ f32x4 mfma16(uint4 a, uint4 b, f32x4 c) {
    union { uint4 u; f16x8 h; } ua, ub;
    ua.u = a; ub.u = b;
    return __builtin_amdgcn_mfma_f32_16x16x32_f16(ua.h, ub.h, c, 0, 0, 0);
}

// ---- prep: build G (32 rows x 64 k, fp16 pairs, LINEAR layout) once ----
// G[r][k] = g[k-1-r] for k-1-r in [0,23), else 0; g = row-sums of the 2D
// normalized kernel (separable 1D tap).
__global__ __launch_bounds__(64) void ssim_prep_kernel(
    const float* __restrict__ w, unsigned* __restrict__ Gg)
{
    const int lane = threadIdx.x;
    float gv = 0.f;
    if (lane < KSIZE) {
        #pragma unroll
        for (int k = 0; k < KSIZE; ++k) gv += w[lane * KSIZE + k];
    }
    for (int idx = lane; idx < 32 * 32; idx += 64) {
        int r = idx >> 5, kd = idx & 31;
        int d0 = 2 * kd - 1 - r;
        float g0 = __shfl(gv, d0 & 63, 64);
        float g1 = __shfl(gv, (d0 + 1) & 63, 64);
        g0 = ((unsigned)d0 < (unsigned)KSIZE) ? g0 : 0.f;
        g1 = ((unsigned)(d0 + 1) < (unsigned)KSIZE) ? g1 : 0.f;
        Gg[idx] = cvtpk(g0, g1);
    }
}

// (256,6): VGPR cap ~85. Est. peak ~76-84 (8 float4 in flight + 32 acc).
// If VGPR_Count shows scratch, revert to LDS staging.
__global__ __launch_bounds__(256, 6) void ssim_main_kernel(
    const float* __restrict__ in, const float* __restrict__ tg,
    const unsigned* __restrict__ Gg, float* __restrict__ partial)
{
    __shared__ __align__(16) unsigned short lds[LDS_TOT];
    __shared__ float swsum[4];

    const int tid = threadIdx.x;
    const int wave = tid >> 6, lane = tid & 63;
    const int m = lane & 15, q = lane >> 4;

    // XCD-aware swizzle (8 XCDs, NBLK % 8 == 0 -> bijective): consecutive
    // tiles (sharing 12-px halos) land on the SAME XCD's L2 (round-6:
    // FETCH 144 -> 49 MB).
    const int blk = (blockIdx.x & 7) * (NBLK / 8) + (blockIdx.x >> 3);
    const int plane = blk >> 8;
    const int t2 = blk & 255;
    const int x0 = (t2 & 15) * 32 - 12;   // 16B-aligned frame origin
    const int y0 = (t2 >> 4) * 32 - 12;
    const float* __restrict__ inp = in + (size_t)plane * (HH * WW);
    const float* __restrict__ tgp = tg + (size_t)plane * (HH * WW);

    // ---- G table load FIRST (so its waitcnt doesn't drain the frag loads) --
    const int gr_ = tid >> 3;                 // 0..31
    const int gdc = (tid & 7) << 2;           // dword col, multiple of 4
    uint4 g4 = *(const uint4*)(Gg + gr_ * 32 + gdc);

    // ---- per-thread h-pass fragment loads (predicated, issued early) ----
    // Thread (wave,m,q) owns frame row wave*16+m, col segments
    // x0 + ks*32 + q*8 + {0,4}. Segments are 16B-aligned, never straddle
    // the image edge ((unsigned)cb <= WW-4 covers cb<0 via wraparound).
    const int gy = y0 + wave * 16 + m;
    const bool rowOK = ((unsigned)gy < (unsigned)HH);
    const float* __restrict__ ri = inp + gy * WW;
    const float* __restrict__ rt = tgp + gy * WW;
    const float4 z4 = {0.f, 0.f, 0.f, 0.f};
    float4 fa[2][2], fb[2][2];
    #pragma unroll
    for (int ks = 0; ks < 2; ++ks)
        #pragma unroll
        for (int sg = 0; sg < 2; ++sg) {
            const int cb = x0 + ks * 32 + q * 8 + sg * 4;
            const bool ok = rowOK && ((unsigned)cb <= (unsigned)(WW - 4));
            fa[ks][sg] = ok ? *(const float4*)(ri + cb) : z4;
            fb[ks][sg] = ok ? *(const float4*)(rt + cb) : z4;
        }

    // ---- G into LDS (swizzled), then the kernel's first barrier ----
    *(uint4*)&lds[G_O + gr_ * 64 + ((gdc << 1) ^ ((gr_ & 7) << 3))] = g4;
    __syncthreads();   // barrier1: G visible (frag loads NOT gated by this)

    // ---- h-pass (MFMA): wave = M-tile (frame rows wave*16..+15) ----
    f32x4 acc[4][2];
    const f32x4 zz = {0.f, 0.f, 0.f, 0.f};
    #pragma unroll
    for (int ch = 0; ch < 4; ++ch) { acc[ch][0] = zz; acc[ch][1] = zz; }

    #pragma unroll
    for (int ks = 0; ks < 2; ++ks) {
        uint4 ua, ub;
        ua.x = cvtpk(fa[ks][0].x, fa[ks][0].y); ua.y = cvtpk(fa[ks][0].z, fa[ks][0].w);
        ua.z = cvtpk(fa[ks][1].x, fa[ks][1].y); ua.w = cvtpk(fa[ks][1].z, fa[ks][1].w);
        ub.x = cvtpk(fb[ks][0].x, fb[ks][0].y); ub.y = cvtpk(fb[ks][0].z, fb[ks][0].w);
        ub.z = cvtpk(fb[ks][1].x, fb[ks][1].y); ub.w = cvtpk(fb[ks][1].z, fb[ks][1].w);
        uint4 uab, uss;
        prod2(ua.x, ub.x, uab.x, uss.x);
        prod2(ua.y, ub.y, uab.y, uss.y);
        prod2(ua.z, ub.z, uab.z, uss.z);
        prod2(ua.w, ub.w, uab.w, uss.w);
        #pragma unroll
        for (int nc = 0; nc < 2; ++nc) {
            const int gr = nc * 16 + m;
            uint4 gf = *(const uint4*)&lds[G_O + gr * 64 + SWZ(gr, ks * 32 + q * 8)];
            acc[0][nc] = mfma16(ua,  gf, acc[0][nc]);
            acc[1][nc] = mfma16(ub,  gf, acc[1][nc]);
            acc[2][nc] = mfma16(uss, gf, acc[2][nc]);
            acc[3][nc] = mfma16(uab, gf, acc[3][nc]);
        }
    }

    // D frag: col = lane&15 (+nc*16), row = q*4 + reg (+wave*16). hb[ch][col][row].
    // HB aliases nothing -> no pre-barrier needed.
    #pragma unroll
    for (int ch = 0; ch < 4; ++ch)
        #pragma unroll
        for (int nc = 0; nc < 2; ++nc) {
            f32x4 a = acc[ch][nc];
            uint2 pk;
            pk.x = cvtpk(a[0], a[1]);
            pk.y = cvtpk(a[2], a[3]);
            const int col = nc * 16 + m;
            const int rb = wave * 16 + q * 4;
            *(uint2*)&lds[HB_O + ch * HB_CH + col * 64 + SWZ(col, rb)] = pk;
        }
    __syncthreads();   // barrier2: HB visible

    // ---- v-pass (MFMA): wave = output quadrant (mrow, nc2) ----
    const int mrow = wave >> 1, nc2 = wave & 1;
    f32x4 av[4];
    #pragma unroll
    for (int ch = 0; ch < 4; ++ch) av[ch] = zz;

    #pragma unroll
    for (int ks = 0; ks < 2; ++ks) {
        const int ar = mrow * 16 + m;
        uint4 ga = *(const uint4*)&lds[G_O + ar * 64 + SWZ(ar, ks * 32 + q * 8)];
        #pragma unroll
        for (int ch = 0; ch < 4; ++ch) {
            const int col = nc2 * 16 + m;
            uint4 ub = *(const uint4*)&lds[HB_O + ch * HB_CH + col * 64 + SWZ(col, ks * 32 + q * 8)];
            av[ch] = mfma16(ga, ub, av[ch]);
        }
    }

    // ---- SSIM map: packed fp32 (v_pk_fma_f32) on px pairs, ONE rcp via
    //      common-denominator combine (den > 0 always; den^4 >= ~6e-29).
    float nacc[2], dacc[2];
    #pragma unroll
    for (int h = 0; h < 2; ++h) {
        f32x2 vx  = {av[0][2 * h], av[0][2 * h + 1]};
        f32x2 vt  = {av[1][2 * h], av[1][2 * h + 1]};
        f32x2 vss = {av[2][2 * h], av[2][2 * h + 1]};
        f32x2 vxt = {av[3][2 * h], av[3][2 * h + 1]};
        f32x2 m1s = vx * vx, m2s = vt * vt, m12 = vx * vt;
        f32x2 p   = m1s + m2s;
        f32x2 s12 = vxt - m12;
        f32x2 num = (2.f * m12 + C1V) * (2.f * s12 + C2V);
        f32x2 den = (p + C1V) * ((vss + C2V) - p);
        nacc[h] = num[0] * den[1] + num[1] * den[0];
        dacc[h] = den[0] * den[1];
    }
    float nn = nacc[0] * dacc[1] + nacc[1] * dacc[0];
    float dd = dacc[0] * dacc[1];
    float lsum = nn * __builtin_amdgcn_rcpf(dd);

    #pragma unroll
    for (int off = 32; off > 0; off >>= 1)
        lsum += __shfl_down(lsum, off, 64);
    if (lane == 0) swsum[wave] = lsum;
    __syncthreads();
    if (tid == 0)
        partial[blk] = swsum[0] + swsum[1] + swsum[2] + swsum[3];
}

__global__ __launch_bounds__(256) void ssim_final_kernel(
    const float* __restrict__ partial, float* __restrict__ out)
{
    __shared__ float swsum[4];
    const int tid = threadIdx.x;
    float s = 0.f;
    const float4* p4 = (const float4*)partial;
    for (int i = tid; i < NBLK / 4; i += 256) {
        float4 v = p4[i];
        s += (v.x + v.y) + (v.z + v.w);
    }
    #pragma unroll
    for (int off = 32; off > 0; off >>= 1)
        s += __shfl_down(s, off, 64);
    if ((tid & 63) == 0) swsum[tid >> 6] = s;
    __syncthreads();
    if (tid == 0)
        out[0] = 1.0f - (swsum[0] + swsum[1] + swsum[2] + swsum[3])
                        * (1.0f / ((float)NPLANES * HH * WW));
}

extern "C" void kernel_launch(void* const* d_in, const int* in_sizes, int n_in,
                              void* d_out, int out_size, void* d_ws, size_t ws_size,
                              hipStream_t stream) {
    const float* inp = (const float*)d_in[0];
    const float* tgt = (const float*)d_in[1];
    const float* wgt = (const float*)d_in[2];
    float* out = (float*)d_out;
    float* partial = (float*)d_ws;                       // NBLK floats
    unsigned* Gg = (unsigned*)((char*)d_ws + NBLK * sizeof(float));  // 4 KB G

    ssim_prep_kernel<<<1, 64, 0, stream>>>(wgt, Gg);
    ssim_main_kernel<<<NBLK, 256, 0, stream>>>(inp, tgt, Gg, partial);
    ssim_final_kernel<<<1, 256, 0, stream>>>(partial, out);
}

// Round 12
// 147.393 us; speedup vs baseline: 1.8635x; 1.8635x over previous
//
#include <hip/hip_runtime.h>
#include <hip/hip_bf16.h>

typedef float f32x4 __attribute__((ext_vector_type(4)));
typedef float f32x2 __attribute__((ext_vector_type(2)));
typedef _Float16 f16x8 __attribute__((ext_vector_type(8)));
typedef _Float16 f16x2 __attribute__((ext_vector_type(2)));
typedef __fp16 h16x2 __attribute__((ext_vector_type(2)));   // builtin's return type

#define HH 512
#define WW 512
#define NPLANES 48              // B*C = 16*3
#define KSIZE 23
#define NBLK (16 * 16 * NPLANES)
#define C1V 1.0e-4f             // 0.01^2
#define C2V 9.0e-4f             // 0.03^2

// LDS layout (ushort indices), ALIASED across phases:
//   stage:  SB [0,3960) SA [3960,7920) rows 0..54, pitch 72
//           OV [7920,8568) zero-filled (SA h-pass overflow rows 55..63 land
//           here; SB overflow lands in SA — finite always)
//           G  [8568,10616) 32x64 fp16, swizzled copy of prep buffer
//   h->v:   HB [0,8192) aliases SA/SB AFTER barrier2 (post h-pass reads);
//           G region is never aliased (v-pass reads it too).
// Total 10616 ushorts = 21232 B -> 7 blocks/CU at (256,7).
// Round-21: re-land the round-10 champion (52.5 µs). Rounds 9+11 proved the
// fragment feed MUST be LDS: global gathers behind barriers expose ~200cy
// latency, and hipcc sinks "early-issued" loads whose live range crosses a
// barrier (r11: VGPR stayed 36, loads landed post-barrier, 182 µs). NEW in
// this round: s_setprio(1) around both MFMA clusters — 7 independent
// blocks/CU at uncorrelated phases gives the scheduler role diversity.
#define SB_O   0
#define SA_O   3960
#define OV_O   7920
#define G_O    8568
#define HB_O   0
#define HB_CH  2048
#define SPITCH 72
#define LDS_TOT 10616

// XOR bank swizzle within a pitch-64 region; preserves 8-ushort (16B) blocks.
#define SWZ(rho, k) ((k) ^ (((rho) & 7) << 3))

// pack two fp32 -> fp16 pair (lo = a, hi = b), RTZ (v_cvt_pkrtz_f16_f32, 1 inst)
__device__ __forceinline__ unsigned cvtpk(float a, float b) {
    union { h16x2 h; unsigned u; } cv;
    cv.h = __builtin_amdgcn_cvt_pkrtz(a, b);
    return cv.u;
}

// Packed fp16 products: pab = a*b, pss = a*a + b*b (v_pk_mul + v_pk_fma).
__device__ __forceinline__ void prod2(unsigned a, unsigned b,
                                      unsigned& pab, unsigned& pss) {
    union U { f16x2 h; unsigned u; } ua, ub, r1, r2;
    ua.u = a; ub.u = b;
    r1.h = ua.h * ub.h;
    r2.h = ua.h * ua.h + ub.h * ub.h;
    pab = r1.u; pss = r2.u;
}

__device__ __forceinline__ f32x4 mfma16(uint4 a, uint4 b, f32x4 c) {
    union { uint4 u; f16x8 h; } ua, ub;
    ua.u = a; ub.u = b;
    return __builtin_amdgcn_mfma_f32_16x16x32_f16(ua.h, ub.h, c, 0, 0, 0);
}

// ---- prep: build G (32 rows x 64 k, fp16 pairs, LINEAR layout) once ----
// G[r][k] = g[k-1-r] for k-1-r in [0,23), else 0; g = row-sums of the 2D
// normalized kernel (separable 1D tap).
__global__ __launch_bounds__(64) void ssim_prep_kernel(
    const float* __restrict__ w, unsigned* __restrict__ Gg)
{
    const int lane = threadIdx.x;
    float gv = 0.f;
    if (lane < KSIZE) {
        #pragma unroll
        for (int k = 0; k < KSIZE; ++k) gv += w[lane * KSIZE + k];
    }
    for (int idx = lane; idx < 32 * 32; idx += 64) {
        int r = idx >> 5, kd = idx & 31;
        int d0 = 2 * kd - 1 - r;
        float g0 = __shfl(gv, d0 & 63, 64);
        float g1 = __shfl(gv, (d0 + 1) & 63, 64);
        g0 = ((unsigned)d0 < (unsigned)KSIZE) ? g0 : 0.f;
        g1 = ((unsigned)(d0 + 1) < (unsigned)KSIZE) ? g1 : 0.f;
        Gg[idx] = cvtpk(g0, g1);
    }
}

// (256,7): measured VGPR=36 (cap ~73 at 7 waves/EU), LDS 21.5 KB
// (7 x 21.5 = 150.5 <= 160 KB) -> 7 blocks/CU, 28 waves/CU ceiling.
__global__ __launch_bounds__(256, 7) void ssim_main_kernel(
    const float* __restrict__ in, const float* __restrict__ tg,
    const unsigned* __restrict__ Gg, float* __restrict__ partial)
{
    __shared__ __align__(16) unsigned short lds[LDS_TOT];
    __shared__ float swsum[4];

    const int tid = threadIdx.x;
    const int wave = tid >> 6, lane = tid & 63;
    const int m = lane & 15, q = lane >> 4;

    // XCD-aware swizzle (8 XCDs, NBLK % 8 == 0 -> bijective): consecutive
    // tiles (sharing 12-px halos) land on the SAME XCD's L2 (round-6:
    // FETCH 144 -> 49 MB).
    const int blk = (blockIdx.x & 7) * (NBLK / 8) + (blockIdx.x >> 3);
    const int plane = blk >> 8;
    const int t2 = blk & 255;
    const int x0 = (t2 & 15) * 32 - 12;   // 16B-aligned frame origin
    const int y0 = (t2 >> 4) * 32 - 12;
    const float* __restrict__ inp = in + (size_t)plane * (HH * WW);
    const float* __restrict__ tgp = tg + (size_t)plane * (HH * WW);

    const bool interior = (x0 >= 0) && (y0 >= 0) && (x0 + 64 <= WW) && (y0 + 55 <= HH);

    // ---- phase A: ISSUE staging loads first (coalesced; latency hidden
    //      under the G-copy / OV-fill below). 55 rows x 8 col-groups = 440
    //      tasks; thread handles tid and tid+256.
    float4 La[2][2], Lb[2][2];
    if (interior) {
        #pragma unroll
        for (int it = 0; it < 2; ++it) {
            int t = tid + it * 256;
            if (t < 440) {
                int r = t >> 3, c8 = (t & 7) << 3;
                const float4* pa = (const float4*)(inp + (y0 + r) * WW + x0 + c8);
                const float4* pb = (const float4*)(tgp + (y0 + r) * WW + x0 + c8);
                La[it][0] = pa[0]; La[it][1] = pa[1];
                Lb[it][0] = pb[0]; Lb[it][1] = pb[1];
            }
        }
    }

    // ---- phase B: copy G into LDS (swizzled) + zero-fill overflow strip ----
    {   // 256 threads x 1 uint4 = 1024 dwords = whole G
        int r = tid >> 3;                    // 0..31
        int dc = (tid & 7) << 2;             // dword col, multiple of 4
        uint4 g4 = *(const uint4*)(Gg + r * 32 + dc);
        *(uint4*)&lds[G_O + r * 64 + (((dc << 1)) ^ ((r & 7) << 3))] = g4;
    }
    if (tid < 81) {
        uint4 z; z.x = z.y = z.z = z.w = 0u;
        *(uint4*)&lds[OV_O + tid * 8] = z;
    }

    // ---- phase C: consume staging loads -> fp16 LDS ----
    if (interior) {
        #pragma unroll
        for (int it = 0; it < 2; ++it) {
            int t = tid + it * 256;
            if (t < 440) {
                int r = t >> 3, c8 = (t & 7) << 3;
                uint4 va, vb;
                va.x = cvtpk(La[it][0].x, La[it][0].y); va.y = cvtpk(La[it][0].z, La[it][0].w);
                va.z = cvtpk(La[it][1].x, La[it][1].y); va.w = cvtpk(La[it][1].z, La[it][1].w);
                vb.x = cvtpk(Lb[it][0].x, Lb[it][0].y); vb.y = cvtpk(Lb[it][0].z, Lb[it][0].w);
                vb.z = cvtpk(Lb[it][1].x, Lb[it][1].y); vb.w = cvtpk(Lb[it][1].z, Lb[it][1].w);
                *(uint4*)&lds[SA_O + r * SPITCH + c8] = va;
                *(uint4*)&lds[SB_O + r * SPITCH + c8] = vb;
            }
        }
    } else {
        unsigned* ldsw = (unsigned*)lds;
        for (int t = tid; t < 55 * 32; t += 256) {
            int r = t >> 5, cd = t & 31;
            int gy = y0 + r, gx = x0 + cd * 2;
            float a0 = 0.f, a1 = 0.f, b0 = 0.f, b1 = 0.f;
            if (gy >= 0 && gy < HH) {
                const float* ri = inp + gy * WW;
                const float* rt = tgp + gy * WW;
                if ((unsigned)gx < (unsigned)WW)       { a0 = ri[gx];     b0 = rt[gx]; }
                if ((unsigned)(gx + 1) < (unsigned)WW) { a1 = ri[gx + 1]; b1 = rt[gx + 1]; }
            }
            ldsw[(SA_O >> 1) + r * 36 + cd] = cvtpk(a0, a1);
            ldsw[(SB_O >> 1) + r * 36 + cd] = cvtpk(b0, b1);
        }
    }
    __syncthreads();   // barrier1: staging + G + OV visible

    // ---- h-pass (MFMA): wave = M-tile (frame rows wave*16..+15). Rows
    //      55..63 read OV zeros / SA junk — finite fp16, killed by zero G taps.
    f32x4 acc[4][2];
    const f32x4 zz = {0.f, 0.f, 0.f, 0.f};
    #pragma unroll
    for (int ch = 0; ch < 4; ++ch) { acc[ch][0] = zz; acc[ch][1] = zz; }

    __builtin_amdgcn_s_setprio(1);   // MFMA cluster: win issue vs other blocks' staging
    #pragma unroll
    for (int ks = 0; ks < 2; ++ks) {
        const int off = (wave * 16 + m) * SPITCH + ks * 32 + q * 8;
        uint4 ua = *(const uint4*)&lds[SA_O + off];
        uint4 ub = *(const uint4*)&lds[SB_O + off];
        uint4 uab, uss;
        prod2(ua.x, ub.x, uab.x, uss.x);
        prod2(ua.y, ub.y, uab.y, uss.y);
        prod2(ua.z, ub.z, uab.z, uss.z);
        prod2(ua.w, ub.w, uab.w, uss.w);
        #pragma unroll
        for (int nc = 0; nc < 2; ++nc) {
            const int gr = nc * 16 + m;
            uint4 gf = *(const uint4*)&lds[G_O + gr * 64 + SWZ(gr, ks * 32 + q * 8)];
            acc[0][nc] = mfma16(ua,  gf, acc[0][nc]);
            acc[1][nc] = mfma16(ub,  gf, acc[1][nc]);
            acc[2][nc] = mfma16(uss, gf, acc[2][nc]);
            acc[3][nc] = mfma16(uab, gf, acc[3][nc]);
        }
    }
    __builtin_amdgcn_s_setprio(0);
    __syncthreads();   // barrier2: all SA/SB reads done -> HB may alias them

    // D frag: col = lane&15 (+nc*16), row = q*4 + reg (+wave*16). hb[ch][col][row].
    #pragma unroll
    for (int ch = 0; ch < 4; ++ch)
        #pragma unroll
        for (int nc = 0; nc < 2; ++nc) {
            f32x4 a = acc[ch][nc];
            uint2 pk;
            pk.x = cvtpk(a[0], a[1]);
            pk.y = cvtpk(a[2], a[3]);
            const int col = nc * 16 + m;
            const int rb = wave * 16 + q * 4;
            *(uint2*)&lds[HB_O + ch * HB_CH + col * 64 + SWZ(col, rb)] = pk;
        }
    __syncthreads();   // barrier3: HB visible

    // ---- v-pass (MFMA): wave = output quadrant (mrow, nc2) ----
    const int mrow = wave >> 1, nc2 = wave & 1;
    f32x4 av[4];
    #pragma unroll
    for (int ch = 0; ch < 4; ++ch) av[ch] = zz;

    __builtin_amdgcn_s_setprio(1);
    #pragma unroll
    for (int ks = 0; ks < 2; ++ks) {
        const int ar = mrow * 16 + m;
        uint4 ga = *(const uint4*)&lds[G_O + ar * 64 + SWZ(ar, ks * 32 + q * 8)];
        #pragma unroll
        for (int ch = 0; ch < 4; ++ch) {
            const int col = nc2 * 16 + m;
            uint4 ub = *(const uint4*)&lds[HB_O + ch * HB_CH + col * 64 + SWZ(col, ks * 32 + q * 8)];
            av[ch] = mfma16(ga, ub, av[ch]);
        }
    }
    __builtin_amdgcn_s_setprio(0);

    // ---- SSIM map: packed fp32 (v_pk_fma_f32) on px pairs, ONE rcp via
    //      common-denominator combine (den > 0 always; den^4 >= ~6e-29).
    float nacc[2], dacc[2];
    #pragma unroll
    for (int h = 0; h < 2; ++h) {
        f32x2 vx  = {av[0][2 * h], av[0][2 * h + 1]};
        f32x2 vt  = {av[1][2 * h], av[1][2 * h + 1]};
        f32x2 vss = {av[2][2 * h], av[2][2 * h + 1]};
        f32x2 vxt = {av[3][2 * h], av[3][2 * h + 1]};
        f32x2 m1s = vx * vx, m2s = vt * vt, m12 = vx * vt;
        f32x2 p   = m1s + m2s;
        f32x2 s12 = vxt - m12;
        f32x2 num = (2.f * m12 + C1V) * (2.f * s12 + C2V);
        f32x2 den = (p + C1V) * ((vss + C2V) - p);
        nacc[h] = num[0] * den[1] + num[1] * den[0];
        dacc[h] = den[0] * den[1];
    }
    float nn = nacc[0] * dacc[1] + nacc[1] * dacc[0];
    float dd = dacc[0] * dacc[1];
    float lsum = nn * __builtin_amdgcn_rcpf(dd);

    #pragma unroll
    for (int off = 32; off > 0; off >>= 1)
        lsum += __shfl_down(lsum, off, 64);
    if (lane == 0) swsum[wave] = lsum;
    __syncthreads();
    if (tid == 0)
        partial[blk] = swsum[0] + swsum[1] + swsum[2] + swsum[3];
}

__global__ __launch_bounds__(256) void ssim_final_kernel(
    const float* __restrict__ partial, float* __restrict__ out)
{
    __shared__ float swsum[4];
    const int tid = threadIdx.x;
    float s = 0.f;
    const float4* p4 = (const float4*)partial;
    for (int i = tid; i < NBLK / 4; i += 256) {
        float4 v = p4[i];
        s += (v.x + v.y) + (v.z + v.w);
    }
    #pragma unroll
    for (int off = 32; off > 0; off >>= 1)
        s += __shfl_down(s, off, 64);
    if ((tid & 63) == 0) swsum[tid >> 6] = s;
    __syncthreads();
    if (tid == 0)
        out[0] = 1.0f - (swsum[0] + swsum[1] + swsum[2] + swsum[3])
                        * (1.0f / ((float)NPLANES * HH * WW));
}

extern "C" void kernel_launch(void* const* d_in, const int* in_sizes, int n_in,
                              void* d_out, int out_size, void* d_ws, size_t ws_size,
                              hipStream_t stream) {
    const float* inp = (const float*)d_in[0];
    const float* tgt = (const float*)d_in[1];
    const float* wgt = (const float*)d_in[2];
    float* out = (float*)d_out;
    float* partial = (float*)d_ws;                       // NBLK floats
    unsigned* Gg = (unsigned*)((char*)d_ws + NBLK * sizeof(float));  // 4 KB G

    ssim_prep_kernel<<<1, 64, 0, stream>>>(wgt, Gg);
    ssim_main_kernel<<<NBLK, 256, 0, stream>>>(inp, tgt, Gg, partial);
    ssim_final_kernel<<<1, 256, 0, stream>>>(partial, out);
}